// Round 1
// baseline (183.164 us; speedup 1.0000x reference)
//
#include <hip/hip_runtime.h>

// upsample2d (up=2) with 5x5 lowpass from [1,3,3,1]*[1,1] = [1,4,6,4,1],
// separable polyphase form. Per-dim weights u/8 = [.125,.5,.75,.5,.125].
// even out 2m   : 0.5*(x[m-1]+x[m])
// odd  out 2m+1 : 0.125*x[m-1] + 0.75*x[m] + 0.125*x[m+1]

#define IH 128
#define IW 128
#define OH 256
#define OW 256

__global__ __launch_bounds__(256) void upsample2d_poly(
    const float* __restrict__ x, float* __restrict__ out, int nplanes)
{
    int idx = blockIdx.x * 256 + threadIdx.x;
    // threads per plane: IH * (IW/4) = 128*32 = 4096
    int p = idx >> 12;
    if (p >= nplanes) return;
    int rem = idx & 4095;
    int my  = rem >> 5;    // input row 0..127
    int tx  = rem & 31;    // 4-col group 0..31
    int mx0 = tx << 2;     // input col base (multiple of 4)

    const float* xp = x + (size_t)p * (IH * IW);

    // load 3 rows x 6 cols (cols mx0-1 .. mx0+4), zero-fill out of range
    float r[3][6];
#pragma unroll
    for (int dr = 0; dr < 3; ++dr) {
        int ry = my + dr - 1;
        if (ry < 0 || ry >= IH) {
#pragma unroll
            for (int j = 0; j < 6; ++j) r[dr][j] = 0.f;
        } else {
            const float* row = xp + ry * IW;
            float4 v = *reinterpret_cast<const float4*>(row + mx0);  // 16B aligned
            r[dr][1] = v.x; r[dr][2] = v.y; r[dr][3] = v.z; r[dr][4] = v.w;
            r[dr][0] = (mx0 > 0)       ? row[mx0 - 1] : 0.f;
            r[dr][5] = (mx0 + 4 < IW)  ? row[mx0 + 4] : 0.f;
        }
    }

    // vertical polyphase: even output row 2*my, odd output row 2*my+1
    float ve[6], vo[6];
#pragma unroll
    for (int j = 0; j < 6; ++j) {
        ve[j] = 0.5f * (r[0][j] + r[1][j]);
        vo[j] = 0.125f * r[0][j] + 0.75f * r[1][j] + 0.125f * r[2][j];
    }

    // horizontal polyphase: 8 output cols starting at 2*mx0
    float oe[8], oo[8];
#pragma unroll
    for (int i = 0; i < 4; ++i) {
        oe[2*i]   = 0.5f * (ve[i] + ve[i+1]);
        oe[2*i+1] = 0.125f * ve[i] + 0.75f * ve[i+1] + 0.125f * ve[i+2];
        oo[2*i]   = 0.5f * (vo[i] + vo[i+1]);
        oo[2*i+1] = 0.125f * vo[i] + 0.75f * vo[i+1] + 0.125f * vo[i+2];
    }

    float* op = out + (size_t)p * (OH * OW);
    int orow = 2 * my;
    int ocol = 2 * mx0;                 // multiple of 8 -> 32B aligned
    float4* d0 = reinterpret_cast<float4*>(op + (size_t)orow * OW + ocol);
    float4* d1 = reinterpret_cast<float4*>(op + (size_t)(orow + 1) * OW + ocol);
    d0[0] = make_float4(oe[0], oe[1], oe[2], oe[3]);
    d0[1] = make_float4(oe[4], oe[5], oe[6], oe[7]);
    d1[0] = make_float4(oo[0], oo[1], oo[2], oo[3]);
    d1[1] = make_float4(oo[4], oo[5], oo[6], oo[7]);
}

extern "C" void kernel_launch(void* const* d_in, const int* in_sizes, int n_in,
                              void* d_out, int out_size, void* d_ws, size_t ws_size,
                              hipStream_t stream)
{
    const float* x = (const float*)d_in[0];
    float* out = (float*)d_out;
    int nplanes = in_sizes[0] / (IH * IW);          // 16*128 = 2048
    int total_threads = nplanes * (IH * (IW / 4));  // 8.4M
    int blocks = (total_threads + 255) / 256;
    upsample2d_poly<<<blocks, 256, 0, stream>>>(x, out, nplanes);
}

// Round 2
// 127.995 us; speedup vs baseline: 1.4310x; 1.4310x over previous
//
#include <hip/hip_runtime.h>

// upsample2d (up=2), 5-tap [1,4,6,4,1]/16, gain=4 -> separable 1D weights /8:
//   even out 2m   : 0.5*(x[m-1]+x[m])
//   odd  out 2m+1 : 0.125*x[m-1] + 0.75*x[m] + 0.125*x[m+1]
//
// Wave-centric: 1 wave = 8 row-pairs of one 128x128 plane. Lane owns 2 input
// cols (float2 load, contiguous), halo via __shfl, 3-row register rolling
// window (each input row loaded once). Stores: float4 @ 4*lane -> contiguous
// 1KB per wave store instruction.

#define IH 128
#define IW 128
#define OW 256

__global__ __launch_bounds__(256) void up2_wave(
    const float* __restrict__ x, float* __restrict__ out)
{
    int gtid = blockIdx.x * 256 + threadIdx.x;
    int wave = gtid >> 6;
    int lane = gtid & 63;
    int p  = wave >> 4;        // plane 0..nplanes-1
    int rg = wave & 15;        // row-group: input rows rg*8 .. rg*8+7
    int m0 = rg * 8;

    const float* xp = x + (size_t)p * (IH * IW);
    float* op = out + (size_t)p * (OW * OW);

    int c0 = lane * 2;

    // rolling rows, 4 cols each: r0=col c0-1, r1=c0, r2=c0+1, r3=c0+2
    float a0,a1,a2,a3, b0,b1,b2,b3;

#define LOADROW(ry, r0, r1, r2, r3)                                   \
    {                                                                 \
        float2 v;                                                     \
        if ((ry) >= 0 && (ry) < IH)  /* wave-uniform branch */        \
            v = *reinterpret_cast<const float2*>(xp + (ry) * IW + c0);\
        else                                                          \
            v = make_float2(0.f, 0.f);                                \
        r1 = v.x; r2 = v.y;                                           \
        r0 = __shfl(v.y, lane - 1);   /* col c0-1 */                  \
        r3 = __shfl(v.x, lane + 1);   /* col c0+2 */                  \
        if (lane == 0)  r0 = 0.f;                                     \
        if (lane == 63) r3 = 0.f;                                     \
    }

    LOADROW(m0 - 1, a0, a1, a2, a3)
    LOADROW(m0,     b0, b1, b2, b3)

#pragma unroll
    for (int i = 0; i < 8; ++i) {
        int m = m0 + i;
        float n0, n1, n2, n3;
        LOADROW(m + 1, n0, n1, n2, n3)

        // vertical polyphase
        float ve0 = 0.5f*(a0+b0), ve1 = 0.5f*(a1+b1);
        float ve2 = 0.5f*(a2+b2), ve3 = 0.5f*(a3+b3);
        float vo0 = 0.125f*a0 + 0.75f*b0 + 0.125f*n0;
        float vo1 = 0.125f*a1 + 0.75f*b1 + 0.125f*n1;
        float vo2 = 0.125f*a2 + 0.75f*b2 + 0.125f*n2;
        float vo3 = 0.125f*a3 + 0.75f*b3 + 0.125f*n3;

        // horizontal polyphase: lane's output cols 4*lane .. 4*lane+3
        float4 re, ro;
        re.x = 0.5f*(ve0+ve1);
        re.y = 0.125f*ve0 + 0.75f*ve1 + 0.125f*ve2;
        re.z = 0.5f*(ve1+ve2);
        re.w = 0.125f*ve1 + 0.75f*ve2 + 0.125f*ve3;
        ro.x = 0.5f*(vo0+vo1);
        ro.y = 0.125f*vo0 + 0.75f*vo1 + 0.125f*vo2;
        ro.z = 0.5f*(vo1+vo2);
        ro.w = 0.125f*vo1 + 0.75f*vo2 + 0.125f*vo3;

        float* dst = op + (size_t)(2*m) * OW + 4*lane;
        *reinterpret_cast<float4*>(dst)      = re;   // even out row, contiguous
        *reinterpret_cast<float4*>(dst + OW) = ro;   // odd out row, contiguous

        a0=b0; a1=b1; a2=b2; a3=b3;
        b0=n0; b1=n1; b2=n2; b3=n3;
    }
#undef LOADROW
}

extern "C" void kernel_launch(void* const* d_in, const int* in_sizes, int n_in,
                              void* d_out, int out_size, void* d_ws, size_t ws_size,
                              hipStream_t stream)
{
    const float* x = (const float*)d_in[0];
    float* out = (float*)d_out;
    int nplanes = in_sizes[0] / (IH * IW);       // 16*128 = 2048
    int waves = nplanes * 16;                    // 16 row-groups per plane
    int total_threads = waves * 64;
    int blocks = (total_threads + 255) / 256;    // 8192
    up2_wave<<<blocks, 256, 0, stream>>>(x, out);
}

// Round 4
// 104.617 us; speedup vs baseline: 1.7508x; 1.2235x over previous
//
#include <hip/hip_runtime.h>

// upsample2d (up=2), separable polyphase of [1,4,6,4,1]/16 with gain 4:
//   even out 2m   : 0.5*(x[m-1]+x[m])
//   odd  out 2m+1 : 0.125*x[m-1] + 0.75*x[m] + 0.125*x[m+1]
//
// Wave = 32-row strip of one 128x128 plane (halo overfetch 34/32).
// Lane owns 2 input cols (float2), halo via __shfl, raw rows prefetched
// 2 iterations ahead so ds_permute never waits directly on vmcnt.
// Output stored non-temporally (don't evict the L3-resident input).
// Note: nontemporal builtin needs clang native vector type, not HIP float4.

#define IH 128
#define IW 128
#define OW 256
#define RSTRIP 32

typedef float f32x4 __attribute__((ext_vector_type(4)));

__global__ __launch_bounds__(256) void up2_wave(
    const float* __restrict__ x, float* __restrict__ out)
{
    int gtid = blockIdx.x * 256 + threadIdx.x;
    int wave = gtid >> 6;
    int lane = gtid & 63;
    int p  = wave >> 2;              // plane
    int sg = wave & 3;               // strip: rows sg*32 .. sg*32+31
    int m0 = sg * RSTRIP;

    const float* xp = x + (size_t)p * (IH * IW);
    float* op = out + (size_t)p * (OW * OW);
    int c0 = lane * 2;

#define RAWLOAD(ry, v)                                                 \
    {                                                                  \
        if ((ry) >= 0 && (ry) < IH)  /* wave-uniform */                \
            v = *reinterpret_cast<const float2*>(xp + (ry) * IW + c0); \
        else                                                           \
            v = make_float2(0.f, 0.f);                                 \
    }

#define SHUF(v, r0, r1, r2, r3)                  \
    {                                            \
        r1 = v.x; r2 = v.y;                      \
        r0 = __shfl(v.y, lane - 1);              \
        r3 = __shfl(v.x, lane + 1);              \
        if (lane == 0)  r0 = 0.f;                \
        if (lane == 63) r3 = 0.f;                \
    }

    float2 vA, vB, vC;                 // raw rows m-1, m, m+1
    RAWLOAD(m0 - 1, vA)
    RAWLOAD(m0,     vB)
    RAWLOAD(m0 + 1, vC)

    float a0,a1,a2,a3, b0,b1,b2,b3;
    SHUF(vA, a0, a1, a2, a3)
    SHUF(vB, b0, b1, b2, b3)

#pragma unroll 4
    for (int i = 0; i < RSTRIP; ++i) {
        int m = m0 + i;

        float2 vD;
        RAWLOAD(m + 2, vD)             // prefetch 2 rows ahead

        float n0, n1, n2, n3;
        SHUF(vC, n0, n1, n2, n3)       // row m+1 (loaded last/prev iter)

        // vertical polyphase
        float ve0 = 0.5f*(a0+b0), ve1 = 0.5f*(a1+b1);
        float ve2 = 0.5f*(a2+b2), ve3 = 0.5f*(a3+b3);
        float vo0 = 0.125f*a0 + 0.75f*b0 + 0.125f*n0;
        float vo1 = 0.125f*a1 + 0.75f*b1 + 0.125f*n1;
        float vo2 = 0.125f*a2 + 0.75f*b2 + 0.125f*n2;
        float vo3 = 0.125f*a3 + 0.75f*b3 + 0.125f*n3;

        // horizontal polyphase: output cols 4*lane .. 4*lane+3
        f32x4 re, ro;
        re.x = 0.5f*(ve0+ve1);
        re.y = 0.125f*ve0 + 0.75f*ve1 + 0.125f*ve2;
        re.z = 0.5f*(ve1+ve2);
        re.w = 0.125f*ve1 + 0.75f*ve2 + 0.125f*ve3;
        ro.x = 0.5f*(vo0+vo1);
        ro.y = 0.125f*vo0 + 0.75f*vo1 + 0.125f*vo2;
        ro.z = 0.5f*(vo1+vo2);
        ro.w = 0.125f*vo1 + 0.75f*vo2 + 0.125f*vo3;

        float* dst = op + (size_t)(2*m) * OW + 4*lane;
        __builtin_nontemporal_store(re, reinterpret_cast<f32x4*>(dst));
        __builtin_nontemporal_store(ro, reinterpret_cast<f32x4*>(dst + OW));

        a0=b0; a1=b1; a2=b2; a3=b3;
        b0=n0; b1=n1; b2=n2; b3=n3;
        vC = vD;
    }
#undef RAWLOAD
#undef SHUF
}

extern "C" void kernel_launch(void* const* d_in, const int* in_sizes, int n_in,
                              void* d_out, int out_size, void* d_ws, size_t ws_size,
                              hipStream_t stream)
{
    const float* x = (const float*)d_in[0];
    float* out = (float*)d_out;
    int nplanes = in_sizes[0] / (IH * IW);         // 2048
    int waves = nplanes * (IH / RSTRIP);           // 8192
    int total_threads = waves * 64;
    int blocks = (total_threads + 255) / 256;      // 2048
    up2_wave<<<blocks, 256, 0, stream>>>(x, out);
}